// Round 6
// baseline (353.712 us; speedup 1.0000x reference)
//
#include <hip/hip_runtime.h>
#include <math.h>

#define NGRAPH 1024
#define NN     256
#define NE     2048
#define EMB    39
#define HD     64
#define NT     512    // 8 waves; 2 blocks/CU (LDS 77.5KB) -> 16 waves/CU; 128-VGPR budget (no spill)
#define K1 205
#define K2 164
#define K3 132

// LDS map (bytes):
//  feat   256*64*4 = 65536   swizzled rows: 16B-unit u stored at u^(row&7) -> b128 conflict-free
//  shared4K        = 4096    sequential lifetimes: epk(B1-B4) -> partial(B6-B7) -> ipart(B8-B9) -> red(B11-B12)
//  col    2048 B   = 2048    CSR column bytes (B4-B5)
//  cnt    260 i    = 1040
//  cur    256 i    = 1024
//  dinv   256 f    = 1024
//  score  256 f    = 1024
//  feats  128 f    = 512
//  pn      64 f    = 256
//  mlp1    64 f    = 256
//  mlp2    32 f    = 128
//  nodemap 256 s   = 512
//  total = 77456  -> 2 blocks/CU (154912 <= 163840)
#define SMEM_BYTES 77456

struct Lds {
    float* feat;
    float* red; unsigned short* epk; float* partial; int* ipart;   // shared 4KB region
    unsigned char* col;
    int* cnt; int* cur; float* dinv; float* score;
    float* feats; float* pn; float* mlp1; float* mlp2; short* nodemap;
};

// packed dual-FMA: d = a*b + c per 32-bit half. IEEE fma per lane-half -> bit-identical
// to fmaf, but 1 VALU issue for 2 elements. SLP won't emit this (round-5 evidence);
// force it via asm. float2 maps to an aligned VGPR pair (VReg_64).
__device__ __forceinline__ float2 pk_fma(float2 a, float2 b, float2 c) {
    float2 d;
    asm("v_pk_fma_f32 %0, %1, %2, %3" : "=v"(d) : "v"(a), "v"(b), "v"(c));
    return d;
}

// swizzled scalar index: row-major [256][64], 16B unit (j>>2) XORed with row&7
__device__ __forceinline__ int fswz(int row, int k) {
    return row * 64 + (((((k >> 2)) ^ (row & 7)) << 2) | (k & 3));
}

template<int FIN>
__device__ __forceinline__ void layer_body(
    const Lds& S, const int* __restrict__ eb,
    const float* __restrict__ W, const float* __restrict__ bvec,
    const float* __restrict__ pvec, int n, int kkeep, int tid)
{
    const int node = tid & 255;
    const int q    = tid >> 8;       // 0/1: feature half (wave-uniform: 4 waves per q)
    // readfirstlane: force SGPR base so W/bias come in via s_load on the scalar pipe
    // (without it the compiler treats tid>>8 as divergent -> per-lane global_load_dword).
    const int joU  = __builtin_amdgcn_readfirstlane(q * 32);
    const int jb0  = q * 8;          // 16B-unit base of this half
    const int lane = tid & 63;
    const bool active = node < n;

    // B0: zero counts; wave0 computes pn = p/||p||
    if (tid < 258) S.cnt[tid] = 0;
    if (tid < 64) {
        float pv = pvec[tid];
        float s2v = pv * pv;
        #pragma unroll
        for (int off = 32; off >= 1; off >>= 1) s2v += __shfl_xor(s2v, off, 64);
        S.pn[tid] = pv * rsqrtf(s2v);
    }
    __syncthreads();

    // B1: pass1 — remap 4 consecutive orig edges/thread; int-atomic degree count
    {
        const int4* src4 = (const int4*)eb;
        const int4* dst4 = (const int4*)(eb + NE);
        int4 sv = src4[tid];
        int4 dv = dst4[tid];
        int ss[4] = { S.nodemap[sv.x], S.nodemap[sv.y], S.nodemap[sv.z], S.nodemap[sv.w] };
        int dd[4] = { S.nodemap[dv.x], S.nodemap[dv.y], S.nodemap[dv.z], S.nodemap[dv.w] };
        unsigned short pk[4];
        #pragma unroll
        for (int t = 0; t < 4; t++) {
            int s = ss[t], d = dd[t];
            pk[t] = 0xFFFFu;
            if ((s | d) >= 0) {                 // both >= 0
                pk[t] = (unsigned short)(s | (d << 8));
                atomicAdd(&S.cnt[d], 1);        // native ds_add_u32
            }
        }
        *(ushort4*)(S.epk + tid * 4) = make_ushort4(pk[0], pk[1], pk[2], pk[3]);
    }
    __syncthreads();

    // B2: fused — exclusive scan of cnt -> offsets, cursors, dinv (single wave)
    if (tid < 64) {
        int base = tid * 4;
        int4 c = *(const int4*)(S.cnt + base);
        int s4 = c.x + c.y + c.z + c.w;
        int x = s4;
        #pragma unroll
        for (int off = 1; off < 64; off <<= 1) {
            int t = __shfl_up(x, off, 64);
            if (tid >= off) x += t;
        }
        int e0 = x - s4;
        int4 off4 = make_int4(e0, e0 + c.x, e0 + c.x + c.y, e0 + c.x + c.y + c.z);
        *(int4*)(S.cnt + base) = off4;
        *(int4*)(S.cur + base) = off4;
        *(float4*)(S.dinv + base) = make_float4(
            rsqrtf((float)(1 + c.x)), rsqrtf((float)(1 + c.y)),
            rsqrtf((float)(1 + c.z)), rsqrtf((float)(1 + c.w)));
        if (tid == 63) S.cnt[256] = x;
    }
    __syncthreads();

    // B4: CSR fill (int-atomic cursors) + h = x@W (x: b128 LDS, W: s_load; pk_fma pairs)
    {
        ushort4 pk4 = *(const ushort4*)(S.epk + tid * 4);
        unsigned short pks[4] = { pk4.x, pk4.y, pk4.z, pk4.w };
        #pragma unroll
        for (int t = 0; t < 4; t++) {
            unsigned pk = pks[t];
            if (pk != 0xFFFFu) {
                int d = pk >> 8;
                int pos = atomicAdd(&S.cur[d], 1);   // ds_add_rtn_u32
                S.col[pos] = (unsigned char)(pk & 0xFFu);
            }
        }
    }
    float2 h2[16];
    if (active) {
        #pragma unroll
        for (int m = 0; m < 16; m++) h2[m] = make_float2(0.f, 0.f);
        const float2* Wp2 = (const float2*)(W + joU);   // (k, joU+2m) -> idx k*32+m
        const float* xrow = S.feat + node * 64;
        const int rs = node & 7;
        if (FIN == EMB) {
            #pragma unroll
            for (int u = 0; u < 9; u++) {
                float4 xv = *(const float4*)(xrow + ((u ^ rs) << 2));
                float xs[4] = { xv.x, xv.y, xv.z, xv.w };
                #pragma unroll
                for (int t = 0; t < 4; t++) {
                    int k = u * 4 + t;
                    float2 xb = make_float2(xs[t], xs[t]);
                    #pragma unroll
                    for (int m = 0; m < 16; m++)
                        h2[m] = pk_fma(xb, Wp2[k * 32 + m], h2[m]);
                }
            }
            #pragma unroll
            for (int k = 36; k < 39; k++) {      // tail: row has only 39 valid cols
                float xv = xrow[((9 ^ rs) << 2) + (k - 36)];
                float2 xb = make_float2(xv, xv);
                #pragma unroll
                for (int m = 0; m < 16; m++)
                    h2[m] = pk_fma(xb, Wp2[k * 32 + m], h2[m]);
            }
        } else {
            #pragma unroll 4
            for (int u = 0; u < 16; u++) {
                float4 xv = *(const float4*)(xrow + ((u ^ rs) << 2));
                float xs[4] = { xv.x, xv.y, xv.z, xv.w };
                #pragma unroll
                for (int t = 0; t < 4; t++) {
                    int k = u * 4 + t;
                    float2 xb = make_float2(xs[t], xs[t]);
                    #pragma unroll
                    for (int m = 0; m < 16; m++)
                        h2[m] = pk_fma(xb, Wp2[k * 32 + m], h2[m]);
                }
            }
        }
    }
    __syncthreads();    // all x reads done before any h write (in-place x->h)

    // B4b: write h half (8 x b128); h registers DIE here (self-term re-read in B5)
    if (active) {
        const int rs = node & 7;
        #pragma unroll
        for (int u = 0; u < 8; u++) {
            float4 v;
            v.x = h2[2*u].x; v.y = h2[2*u].y; v.z = h2[2*u+1].x; v.w = h2[2*u+1].y;
            *(float4*)(S.feat + node * 64 + (((jb0 + u) ^ rs) << 2)) = v;
        }
    }
    __syncthreads();

    // B5: gather agg (pk_fma); self-term re-read from own LDS row; out IN PLACE of s2
    float2 s2[16];          // becomes `out` after the epilogue loop
    float sc = 0.f;
    if (active) {
        int o0 = S.cnt[node], o1 = S.cnt[node + 1];
        #pragma unroll
        for (int m = 0; m < 16; m++) s2[m] = make_float2(0.f, 0.f);
        if (o0 < o1) {
            int sN = S.col[o0];                  // prefetch breaks col->hsrc chain
            for (int e = o0; e < o1; e++) {
                int s = sN;
                int en = (e + 1 < o1) ? (e + 1) : e;
                sN = S.col[en];
                float dv = S.dinv[s];
                float2 dvb = make_float2(dv, dv);
                const float* hs = S.feat + s * 64;
                const int ssz = s & 7;
                #pragma unroll
                for (int u = 0; u < 8; u++) {
                    float4 hv = *(const float4*)(hs + (((jb0 + u) ^ ssz) << 2));
                    s2[2*u]   = pk_fma(dvb, make_float2(hv.x, hv.y), s2[2*u]);
                    s2[2*u+1] = pk_fma(dvb, make_float2(hv.z, hv.w), s2[2*u+1]);
                }
            }
        }
        float dvd = S.dinv[node];
        float invdeg = dvd * dvd;               // 1/deg
        float2 dv2 = make_float2(dvd, dvd);
        float2 iv2 = make_float2(invdeg, invdeg);
        const float2* b2p = (const float2*)(bvec + joU);   // SGPR base -> s_load
        const float2* pn2 = (const float2*)(S.pn + joU);
        const float* hown = S.feat + node * 64;
        const int rs = node & 7;
        #pragma unroll
        for (int u = 0; u < 8; u++) {
            float4 hv = *(const float4*)(hown + (((jb0 + u) ^ rs) << 2));
            float2 t0 = pk_fma(iv2, make_float2(hv.x, hv.y), b2p[2*u]);
            float2 t1 = pk_fma(iv2, make_float2(hv.z, hv.w), b2p[2*u+1]);
            float2 o0 = pk_fma(dv2, s2[2*u],   t0);
            float2 o1 = pk_fma(dv2, s2[2*u+1], t1);
            o0.x = fmaxf(o0.x, 0.f); o0.y = fmaxf(o0.y, 0.f);
            o1.x = fmaxf(o1.x, 0.f); o1.y = fmaxf(o1.y, 0.f);
            s2[2*u] = o0; s2[2*u+1] = o1;        // in place: s2 is now `out`
            float2 p0 = pn2[2*u], p1 = pn2[2*u+1];
            sc = fmaf(o0.x, p0.x, sc); sc = fmaf(o0.y, p0.y, sc);
            sc = fmaf(o1.x, p1.x, sc); sc = fmaf(o1.y, p1.y, sc);
        }
    }
    __syncthreads();    // col + feat + epk reads done -> partial may use shared region

    // B6: score partials (2 per node)
    S.partial[tid] = sc;
    __syncthreads();

    // B7: score = tanh(sum of 2 partials)
    if (tid < 256) S.score[tid] = tanhf(S.partial[tid] + S.partial[tid + 256]);
    __syncthreads();

    // B8: rank by counting (2 threads/node, 128-wide slices; b128 broadcast reads)
    {
        int j0 = joU * 4;                        // q*128, scalar
        int j1 = (j0 + 128 < n) ? (j0 + 128) : n;
        float si = S.score[node];
        int c = 0;
        int j = j0;
        for (; j + 4 <= j1; j += 4) {
            float4 s4 = *(const float4*)&S.score[j];
            c += (s4.x > si) || (s4.x == si && (j + 0) < node);
            c += (s4.y > si) || (s4.y == si && (j + 1) < node);
            c += (s4.z > si) || (s4.z == si && (j + 2) < node);
            c += (s4.w > si) || (s4.w == si && (j + 3) < node);
        }
        for (; j < j1; j++) {
            float sj = S.score[j];
            c += (sj > si) || (sj == si && j < node);
        }
        S.ipart[tid] = c;
    }
    __syncthreads();

    // B9: rank into cur (cursors dead)
    if (tid < 256) S.cur[tid] = S.ipart[tid] + S.ipart[tid + 256];
    __syncthreads();

    // B10: compose cumulative nodemap; pooled rows written from out regs (b128, permuted)
    if (tid < 256) {
        int m = S.nodemap[tid];
        if (m >= 0) {
            int r = S.cur[m];
            S.nodemap[tid] = (short)((r < kkeep) ? r : -1);
        }
    }
    if (active) {
        int r = S.cur[node];
        if (r < kkeep) {
            float v = S.score[node];
            const int rr = r & 7;
            #pragma unroll
            for (int u = 0; u < 8; u++) {
                float4 w4;
                w4.x = s2[2*u].x * v;   w4.y = s2[2*u].y * v;
                w4.z = s2[2*u+1].x * v; w4.w = s2[2*u+1].y * v;
                *(float4*)(S.feat + r * 64 + (((jb0 + u) ^ rr) << 2)) = w4;
            }
        }
    }
    __syncthreads();

    // B11: readout partials (wave-strided rows, lane=feature; row read = bank permutation)
    {
        int w = tid >> 6;
        float mx = -3.4e38f, sm = 0.f;
        for (int rr = w; rr < kkeep; rr += 8) {
            float v = S.feat[rr * 64 + ((((lane >> 2) ^ (rr & 7)) << 2) | (lane & 3))];
            mx = fmaxf(mx, v);
            sm += v;
        }
        S.red[w * 64 + lane]       = mx;
        S.red[512 + w * 64 + lane] = sm;
    }
    __syncthreads();

    // B12: combine into feats
    if (tid < 64) {
        float mx = S.red[tid], sm = S.red[512 + tid];
        #pragma unroll
        for (int w = 1; w < 8; w++) {
            mx = fmaxf(mx, S.red[w * 64 + tid]);
            sm += S.red[512 + w * 64 + tid];
        }
        S.feats[tid]      += mx;
        S.feats[64 + tid] += sm / (float)kkeep;
    }
    __syncthreads();
}

__global__ __launch_bounds__(NT, 4) void gnn_pool_kernel(
    const float* __restrict__ gx, const int* __restrict__ gedge,
    const float* __restrict__ W1, const float* __restrict__ b1, const float* __restrict__ p1,
    const float* __restrict__ W2, const float* __restrict__ b2, const float* __restrict__ p2,
    const float* __restrict__ W3, const float* __restrict__ b3, const float* __restrict__ p3,
    const float* __restrict__ lW1, const float* __restrict__ lb1,
    const float* __restrict__ lW2, const float* __restrict__ lb2,
    const float* __restrict__ lW3, const float* __restrict__ lb3,
    float* __restrict__ gout)
{
    extern __shared__ __align__(16) char smem_raw[];
    Lds S;
    S.feat    = (float*)smem_raw;                         // 16384 f
    S.red     = S.feat + NN * 64;                         // 1024 f shared region
    S.epk     = (unsigned short*)S.red;                   // alias (B1-B4)
    S.partial = S.red;                                    // alias (B6-B7)
    S.ipart   = (int*)S.red;                              // alias (B8-B9)
    S.col     = (unsigned char*)(S.red + 1024);           // 2048 B
    S.cnt     = (int*)(S.col + 2048);                     // 260 i
    S.cur     = S.cnt + 260;                              // 256 i
    S.dinv    = (float*)(S.cur + 256);                    // 256 f
    S.score   = S.dinv + 256;                             // 256 f
    S.feats   = S.score + 256;                            // 128 f
    S.pn      = S.feats + 128;                            // 64 f
    S.mlp1    = S.pn + 64;                                // 64 f
    S.mlp2    = S.mlp1 + 64;                              // 32 f
    S.nodemap = (short*)(S.mlp2 + 32);                    // 256 s

    const int tid = threadIdx.x;
    const int b   = blockIdx.x;
    const int* eb = gedge + (size_t)b * 2 * NE;

    // init: x -> swizzled feat rows (float4 global loads), identity nodemap, zero feats
    {
        const float4* xb4 = (const float4*)(gx + (size_t)b * NN * EMB);
        for (int i = tid; i < (NN * EMB) / 4; i += NT) {   // 2496 vec4
            float4 v = xb4[i];
            int g = i * 4;
            float vs[4] = { v.x, v.y, v.z, v.w };
            #pragma unroll
            for (int t = 0; t < 4; t++) {
                int gg = g + t;
                int nd = gg / EMB;
                int k  = gg - nd * EMB;
                S.feat[fswz(nd, k)] = vs[t];
            }
        }
        if (tid < NN) S.nodemap[tid] = (short)tid;
        if (tid < 2 * HD) S.feats[tid] = 0.f;
    }
    __syncthreads();

    layer_body<EMB>(S, eb, W1, b1, p1, NN, K1, tid);
    layer_body<HD >(S, eb, W2, b2, p2, K1, K2, tid);
    layer_body<HD >(S, eb, W3, b3, p3, K2, K3, tid);

    // final MLP: 128 -> 64 -> 32 -> 1, sigmoid
    if (tid < 64) {
        float a = lb1[tid];
        for (int i = 0; i < 2 * HD; i++) a = fmaf(S.feats[i], lW1[i * 64 + tid], a);
        S.mlp1[tid] = fmaxf(a, 0.f);
    }
    __syncthreads();
    if (tid < 32) {
        float a = lb2[tid];
        for (int i = 0; i < 64; i++) a = fmaf(S.mlp1[i], lW2[i * 32 + tid], a);
        S.mlp2[tid] = fmaxf(a, 0.f);
    }
    __syncthreads();
    if (tid == 0) {
        float a = lb3[0];
        for (int i = 0; i < 32; i++) a = fmaf(S.mlp2[i], lW3[i], a);
        gout[b] = 1.0f / (1.0f + expf(-a));
    }
}

extern "C" void kernel_launch(void* const* d_in, const int* in_sizes, int n_in,
                              void* d_out, int out_size, void* d_ws, size_t ws_size,
                              hipStream_t stream) {
    const float* gx    = (const float*)d_in[0];
    const int*   gedge = (const int*)d_in[1];
    const float* W1 = (const float*)d_in[2];
    const float* b1 = (const float*)d_in[3];
    const float* p1 = (const float*)d_in[4];
    const float* W2 = (const float*)d_in[5];
    const float* b2 = (const float*)d_in[6];
    const float* p2 = (const float*)d_in[7];
    const float* W3 = (const float*)d_in[8];
    const float* b3 = (const float*)d_in[9];
    const float* p3 = (const float*)d_in[10];
    const float* lW1 = (const float*)d_in[11];
    const float* lb1 = (const float*)d_in[12];
    const float* lW2 = (const float*)d_in[13];
    const float* lb2 = (const float*)d_in[14];
    const float* lW3 = (const float*)d_in[15];
    const float* lb3 = (const float*)d_in[16];
    float* gout = (float*)d_out;

    (void)hipFuncSetAttribute((const void*)gnn_pool_kernel,
                              hipFuncAttributeMaxDynamicSharedMemorySize, SMEM_BYTES);

    gnn_pool_kernel<<<NGRAPH, NT, SMEM_BYTES, stream>>>(
        gx, gedge, W1, b1, p1, W2, b2, p2, W3, b3, p3,
        lW1, lb1, lW2, lb2, lW3, lb3, gout);
}

// Round 7
// 306.249 us; speedup vs baseline: 1.1550x; 1.1550x over previous
//
#include <hip/hip_runtime.h>
#include <math.h>

#define NGRAPH 1024
#define NN     256
#define NE     2048
#define EMB    39
#define HD     64
#define NT     512    // 8 waves; 2 blocks/CU (LDS 78.2KB) -> 16 waves/CU; no spill at 128-VGPR budget
#define K1 205
#define K2 164
#define K3 132

// LDS map (bytes):
//  feat   256*64*4 = 65536   swizzled rows: 16B-unit u stored at u^(row&7) -> b128 conflict-free
//  shared4K        = 4096    sequential lifetimes: epk(B1-B4) -> partial(B6-B7) -> ipart(B8-B9) -> red(B11-B12)
//  col    2048 B   = 2048    CSR column bytes (B4-B5)
//  cnt    260 i    = 1040
//  cur    256 i    = 1024
//  dinv   256 f    = 1024
//  score  256 f    = 1024    (also int scratch for degree-rank: zeroed B0, atomicAdd B4, scatter B4b)
//  feats  128 f    = 512
//  pn      64 f    = 256
//  mlp1    64 f    = 256
//  mlp2    32 f    = 128
//  nodemap 256 s   = 512
//  degu8  256 B    = 256     per-node degree clamped to 255 (written B2)
//  dsort  256 s    = 512     degree-sorted node permutation: dsort[rank] = node
//  total = 78224  -> 2 blocks/CU (156448 <= 163840)
#define SMEM_BYTES 78224

struct Lds {
    float* feat;
    float* red; unsigned short* epk; float* partial; int* ipart;   // shared 4KB region
    unsigned char* col;
    int* cnt; int* cur; float* dinv; float* score;
    float* feats; float* pn; float* mlp1; float* mlp2; short* nodemap;
    unsigned char* degu8; short* dsort;
};

// swizzled scalar index: row-major [256][64], 16B unit (j>>2) XORed with row&7
__device__ __forceinline__ int fswz(int row, int k) {
    return row * 64 + (((((k >> 2)) ^ (row & 7)) << 2) | (k & 3));
}

template<int FIN>
__device__ __forceinline__ void layer_body(
    const Lds& S, const int* __restrict__ eb,
    const float* __restrict__ W, const float* __restrict__ bvec,
    const float* __restrict__ pvec, int n, int kkeep, int tid)
{
    const int node = tid & 255;
    const int q    = tid >> 8;       // 0/1: feature half (wave-uniform at runtime)
    // readfirstlane: force SGPR base so W/bias come in via s_load on the scalar pipe
    // (without it the compiler treats tid>>8 as divergent -> per-lane global_load_dword).
    const int joU  = __builtin_amdgcn_readfirstlane(q * 32);
    const int jb0  = q * 8;          // 16B-unit base of this half
    const int lane = tid & 63;
    const bool active = node < n;    // keyed on raw node id (B4 matmul)
    int* scoreInt = (int*)S.score;   // degree-rank scratch (score dead between layers)

    // B0: zero counts + rank scratch; wave0 computes pn = p/||p||
    if (tid < 258) S.cnt[tid] = 0;
    if (tid < 256) scoreInt[tid] = 0;
    if (tid < 64) {
        float pv = pvec[tid];
        float s2v = pv * pv;
        #pragma unroll
        for (int off = 32; off >= 1; off >>= 1) s2v += __shfl_xor(s2v, off, 64);
        S.pn[tid] = pv * rsqrtf(s2v);
    }
    __syncthreads();

    // B1: pass1 — remap 4 consecutive orig edges/thread; int-atomic degree count
    {
        const int4* src4 = (const int4*)eb;
        const int4* dst4 = (const int4*)(eb + NE);
        int4 sv = src4[tid];
        int4 dv = dst4[tid];
        int ss[4] = { S.nodemap[sv.x], S.nodemap[sv.y], S.nodemap[sv.z], S.nodemap[sv.w] };
        int dd[4] = { S.nodemap[dv.x], S.nodemap[dv.y], S.nodemap[dv.z], S.nodemap[dv.w] };
        unsigned short pk[4];
        #pragma unroll
        for (int t = 0; t < 4; t++) {
            int s = ss[t], d = dd[t];
            pk[t] = 0xFFFFu;
            if ((s | d) >= 0) {                 // both >= 0
                pk[t] = (unsigned short)(s | (d << 8));
                atomicAdd(&S.cnt[d], 1);        // native ds_add_u32
            }
        }
        *(ushort4*)(S.epk + tid * 4) = make_ushort4(pk[0], pk[1], pk[2], pk[3]);
    }
    __syncthreads();

    // B2: fused — exclusive scan of cnt -> offsets, cursors, dinv, packed u8 degrees
    if (tid < 64) {
        int base = tid * 4;
        int4 c = *(const int4*)(S.cnt + base);
        int s4 = c.x + c.y + c.z + c.w;
        int x = s4;
        #pragma unroll
        for (int off = 1; off < 64; off <<= 1) {
            int t = __shfl_up(x, off, 64);
            if (tid >= off) x += t;
        }
        int e0 = x - s4;
        int4 off4 = make_int4(e0, e0 + c.x, e0 + c.x + c.y, e0 + c.x + c.y + c.z);
        *(int4*)(S.cnt + base) = off4;
        *(int4*)(S.cur + base) = off4;
        *(float4*)(S.dinv + base) = make_float4(
            rsqrtf((float)(1 + c.x)), rsqrtf((float)(1 + c.y)),
            rsqrtf((float)(1 + c.z)), rsqrtf((float)(1 + c.w)));
        // clamped u8 degrees (clamp only affects sort quality, not correctness)
        unsigned d0 = c.x > 255 ? 255u : (unsigned)c.x;
        unsigned d1 = c.y > 255 ? 255u : (unsigned)c.y;
        unsigned d2 = c.z > 255 ? 255u : (unsigned)c.z;
        unsigned d3 = c.w > 255 ? 255u : (unsigned)c.w;
        ((unsigned*)S.degu8)[tid] = d0 | (d1 << 8) | (d2 << 16) | (d3 << 24);
        if (tid == 63) S.cnt[256] = x;
    }
    __syncthreads();

    // B4: degree-rank count (exact integer counting sort, ties by index) +
    //     CSR fill (int-atomic cursors) + h = x@W (x: b128 LDS, W: s_load)
    {
        int dg = S.degu8[node];
        int j0 = q * 128;
        const unsigned* dw = (const unsigned*)(S.degu8 + j0);
        int c = 0;
        #pragma unroll 8
        for (int w = 0; w < 32; w++) {
            unsigned wv = dw[w];
            int j = j0 + w * 4;
            #pragma unroll
            for (int t = 0; t < 4; t++) {
                int dj = (wv >> (8 * t)) & 255;
                c += (dj > dg) || (dj == dg && (j + t) < node);
            }
        }
        atomicAdd(&scoreInt[node], c);          // rank among all 256 ids
    }
    {
        ushort4 pk4 = *(const ushort4*)(S.epk + tid * 4);
        unsigned short pks[4] = { pk4.x, pk4.y, pk4.z, pk4.w };
        #pragma unroll
        for (int t = 0; t < 4; t++) {
            unsigned pk = pks[t];
            if (pk != 0xFFFFu) {
                int d = pk >> 8;
                int pos = atomicAdd(&S.cur[d], 1);   // ds_add_rtn_u32
                S.col[pos] = (unsigned char)(pk & 0xFFu);
            }
        }
    }
    float h[32];
    if (active) {
        #pragma unroll
        for (int j = 0; j < 32; j++) h[j] = 0.f;
        const float* Wp   = W + joU;             // SGPR base -> scalar W loads
        const float* xrow = S.feat + node * 64;
        const int rs = node & 7;
        if (FIN == EMB) {
            #pragma unroll
            for (int u = 0; u < 9; u++) {
                float4 xv = *(const float4*)(xrow + ((u ^ rs) << 2));
                float xs[4] = { xv.x, xv.y, xv.z, xv.w };
                #pragma unroll
                for (int t = 0; t < 4; t++) {
                    int k = u * 4 + t;
                    #pragma unroll
                    for (int j = 0; j < 32; j++) h[j] = fmaf(xs[t], Wp[k * HD + j], h[j]);
                }
            }
            #pragma unroll
            for (int k = 36; k < 39; k++) {      // tail: row has only 39 valid cols
                float xv = xrow[((9 ^ rs) << 2) + (k - 36)];
                #pragma unroll
                for (int j = 0; j < 32; j++) h[j] = fmaf(xv, Wp[k * HD + j], h[j]);
            }
        } else {
            #pragma unroll 4
            for (int u = 0; u < 16; u++) {
                float4 xv = *(const float4*)(xrow + ((u ^ rs) << 2));
                float xs[4] = { xv.x, xv.y, xv.z, xv.w };
                #pragma unroll
                for (int t = 0; t < 4; t++) {
                    int k = u * 4 + t;
                    #pragma unroll
                    for (int j = 0; j < 32; j++) h[j] = fmaf(xs[t], Wp[k * HD + j], h[j]);
                }
            }
        }
    }
    __syncthreads();    // all x reads done before any h write (in-place x->h)

    // B4b: write h rows (b128) + scatter degree-sort permutation; h regs die here
    if (active) {
        const int rs = node & 7;
        #pragma unroll
        for (int u = 0; u < 8; u++) {
            float4 v;
            v.x = h[u * 4 + 0]; v.y = h[u * 4 + 1]; v.z = h[u * 4 + 2]; v.w = h[u * 4 + 3];
            *(float4*)(S.feat + node * 64 + (((jb0 + u) ^ rs) << 2)) = v;
        }
    }
    if (tid < 256) S.dsort[scoreInt[tid]] = (short)tid;   // bijective: rank -> node
    __syncthreads();

    // B5: gather for node nd = dsort[node] (degree-sorted lanes: wave-max-degree halves);
    // self-term re-read from own LDS row; out computed IN PLACE of s1
    const int nd = S.dsort[node];
    const bool act5 = nd < n;        // dead ids sort to tail -> whole tail waves idle
    float s1[32];                    // becomes `out` after the epilogue loop
    float sc = 0.f;
    if (act5) {
        int o0 = S.cnt[nd], o1 = S.cnt[nd + 1];
        #pragma unroll
        for (int j = 0; j < 32; j++) s1[j] = 0.f;
        if (o0 < o1) {
            int sN = S.col[o0];                  // prefetch breaks col->hsrc chain
            for (int e = o0; e < o1; e++) {
                int s = sN;
                int en = (e + 1 < o1) ? (e + 1) : e;
                sN = S.col[en];
                float dv = S.dinv[s];
                const float* hs = S.feat + s * 64;
                const int ssz = s & 7;
                #pragma unroll
                for (int u = 0; u < 8; u++) {
                    float4 hv = *(const float4*)(hs + (((jb0 + u) ^ ssz) << 2));
                    s1[u * 4 + 0] = fmaf(dv, hv.x, s1[u * 4 + 0]);
                    s1[u * 4 + 1] = fmaf(dv, hv.y, s1[u * 4 + 1]);
                    s1[u * 4 + 2] = fmaf(dv, hv.z, s1[u * 4 + 2]);
                    s1[u * 4 + 3] = fmaf(dv, hv.w, s1[u * 4 + 3]);
                }
            }
        }
        float dvd = S.dinv[nd];
        float invdeg = dvd * dvd;               // 1/deg
        const float* bU   = bvec + joU;         // SGPR base -> scalar bias loads
        const float* hown = S.feat + nd * 64;
        const int rs = nd & 7;
        #pragma unroll
        for (int u = 0; u < 8; u++) {
            float4 hv = *(const float4*)(hown + (((jb0 + u) ^ rs) << 2));
            float hs[4] = { hv.x, hv.y, hv.z, hv.w };
            #pragma unroll
            for (int t = 0; t < 4; t++) {
                int j = u * 4 + t;
                float o = fmaf(dvd, s1[j], fmaf(hs[t], invdeg, bU[j]));
                o = fmaxf(o, 0.f);
                s1[j] = o;                       // in place: s1 is now `out`
                sc = fmaf(o, S.pn[joU + j], sc);
            }
        }
    }
    __syncthreads();    // col + feat + epk + scoreInt reads done -> shared region reusable

    // B6: score partials (2 per node, keyed by tid; both halves of a node share nd)
    S.partial[tid] = sc;
    __syncthreads();

    // B7: score[nd] = tanh(sum of the node's 2 partials)
    if (tid < 256) {
        int nd2 = S.dsort[tid];
        S.score[nd2] = tanhf(S.partial[tid] + S.partial[tid + 256]);
    }
    __syncthreads();

    // B8: rank by counting (2 threads/node, 128-wide slices; b128 broadcast reads)
    {
        int c = 0;
        if (act5) {
            int j0 = joU * 4;                    // q*128, scalar
            int j1 = (j0 + 128 < n) ? (j0 + 128) : n;
            float si = S.score[nd];
            int j = j0;
            for (; j + 4 <= j1; j += 4) {
                float4 s4 = *(const float4*)&S.score[j];
                c += (s4.x > si) || (s4.x == si && (j + 0) < nd);
                c += (s4.y > si) || (s4.y == si && (j + 1) < nd);
                c += (s4.z > si) || (s4.z == si && (j + 2) < nd);
                c += (s4.w > si) || (s4.w == si && (j + 3) < nd);
            }
            for (; j < j1; j++) {
                float sj = S.score[j];
                c += (sj > si) || (sj == si && j < nd);
            }
        }
        S.ipart[tid] = c;
    }
    __syncthreads();

    // B9: rank into cur (cursors dead), scattered to node id
    if (tid < 256) {
        int nd2 = S.dsort[tid];
        S.cur[nd2] = S.ipart[tid] + S.ipart[tid + 256];
    }
    __syncthreads();

    // B10: compose cumulative nodemap; pooled rows written from out regs (b128, permuted)
    if (tid < 256) {
        int m = S.nodemap[tid];
        if (m >= 0) {
            int r = S.cur[m];
            S.nodemap[tid] = (short)((r < kkeep) ? r : -1);
        }
    }
    if (act5) {
        int r = S.cur[nd];
        if (r < kkeep) {
            float v = S.score[nd];
            const int rr = r & 7;
            #pragma unroll
            for (int u = 0; u < 8; u++) {
                float4 w4;
                w4.x = s1[u * 4 + 0] * v; w4.y = s1[u * 4 + 1] * v;
                w4.z = s1[u * 4 + 2] * v; w4.w = s1[u * 4 + 3] * v;
                *(float4*)(S.feat + r * 64 + (((jb0 + u) ^ rr) << 2)) = w4;
            }
        }
    }
    __syncthreads();

    // B11: readout partials (wave-strided rows, lane=feature; row read = bank permutation)
    {
        int w = tid >> 6;
        float mx = -3.4e38f, sm = 0.f;
        for (int rr = w; rr < kkeep; rr += 8) {
            float v = S.feat[rr * 64 + ((((lane >> 2) ^ (rr & 7)) << 2) | (lane & 3))];
            mx = fmaxf(mx, v);
            sm += v;
        }
        S.red[w * 64 + lane]       = mx;
        S.red[512 + w * 64 + lane] = sm;
    }
    __syncthreads();

    // B12: combine into feats
    if (tid < 64) {
        float mx = S.red[tid], sm = S.red[512 + tid];
        #pragma unroll
        for (int w = 1; w < 8; w++) {
            mx = fmaxf(mx, S.red[w * 64 + tid]);
            sm += S.red[512 + w * 64 + tid];
        }
        S.feats[tid]      += mx;
        S.feats[64 + tid] += sm / (float)kkeep;
    }
    __syncthreads();
}

__global__ __launch_bounds__(NT, 4) void gnn_pool_kernel(
    const float* __restrict__ gx, const int* __restrict__ gedge,
    const float* __restrict__ W1, const float* __restrict__ b1, const float* __restrict__ p1,
    const float* __restrict__ W2, const float* __restrict__ b2, const float* __restrict__ p2,
    const float* __restrict__ W3, const float* __restrict__ b3, const float* __restrict__ p3,
    const float* __restrict__ lW1, const float* __restrict__ lb1,
    const float* __restrict__ lW2, const float* __restrict__ lb2,
    const float* __restrict__ lW3, const float* __restrict__ lb3,
    float* __restrict__ gout)
{
    extern __shared__ __align__(16) char smem_raw[];
    Lds S;
    S.feat    = (float*)smem_raw;                         // 16384 f
    S.red     = S.feat + NN * 64;                         // 1024 f shared region
    S.epk     = (unsigned short*)S.red;                   // alias (B1-B4)
    S.partial = S.red;                                    // alias (B6-B7)
    S.ipart   = (int*)S.red;                              // alias (B8-B9)
    S.col     = (unsigned char*)(S.red + 1024);           // 2048 B
    S.cnt     = (int*)(S.col + 2048);                     // 260 i
    S.cur     = S.cnt + 260;                              // 256 i
    S.dinv    = (float*)(S.cur + 256);                    // 256 f
    S.score   = S.dinv + 256;                             // 256 f (+int scratch)
    S.feats   = S.score + 256;                            // 128 f
    S.pn      = S.feats + 128;                            // 64 f
    S.mlp1    = S.pn + 64;                                // 64 f
    S.mlp2    = S.mlp1 + 64;                              // 32 f
    S.nodemap = (short*)(S.mlp2 + 32);                    // 256 s
    S.degu8   = (unsigned char*)(S.nodemap + 256);        // 256 B
    S.dsort   = (short*)(S.degu8 + 256);                  // 256 s

    const int tid = threadIdx.x;
    const int b   = blockIdx.x;
    const int* eb = gedge + (size_t)b * 2 * NE;

    // init: x -> swizzled feat rows (float4 global loads), identity nodemap, zero feats
    {
        const float4* xb4 = (const float4*)(gx + (size_t)b * NN * EMB);
        for (int i = tid; i < (NN * EMB) / 4; i += NT) {   // 2496 vec4
            float4 v = xb4[i];
            int g = i * 4;
            float vs[4] = { v.x, v.y, v.z, v.w };
            #pragma unroll
            for (int t = 0; t < 4; t++) {
                int gg = g + t;
                int nd = gg / EMB;
                int k  = gg - nd * EMB;
                S.feat[fswz(nd, k)] = vs[t];
            }
        }
        if (tid < NN) S.nodemap[tid] = (short)tid;
        if (tid < 2 * HD) S.feats[tid] = 0.f;
    }
    __syncthreads();

    layer_body<EMB>(S, eb, W1, b1, p1, NN, K1, tid);
    layer_body<HD >(S, eb, W2, b2, p2, K1, K2, tid);
    layer_body<HD >(S, eb, W3, b3, p3, K2, K3, tid);

    // final MLP: 128 -> 64 -> 32 -> 1, sigmoid
    if (tid < 64) {
        float a = lb1[tid];
        for (int i = 0; i < 2 * HD; i++) a = fmaf(S.feats[i], lW1[i * 64 + tid], a);
        S.mlp1[tid] = fmaxf(a, 0.f);
    }
    __syncthreads();
    if (tid < 32) {
        float a = lb2[tid];
        for (int i = 0; i < 64; i++) a = fmaf(S.mlp1[i], lW2[i * 32 + tid], a);
        S.mlp2[tid] = fmaxf(a, 0.f);
    }
    __syncthreads();
    if (tid == 0) {
        float a = lb3[0];
        for (int i = 0; i < 32; i++) a = fmaf(S.mlp2[i], lW3[i], a);
        gout[b] = 1.0f / (1.0f + expf(-a));
    }
}

extern "C" void kernel_launch(void* const* d_in, const int* in_sizes, int n_in,
                              void* d_out, int out_size, void* d_ws, size_t ws_size,
                              hipStream_t stream) {
    const float* gx    = (const float*)d_in[0];
    const int*   gedge = (const int*)d_in[1];
    const float* W1 = (const float*)d_in[2];
    const float* b1 = (const float*)d_in[3];
    const float* p1 = (const float*)d_in[4];
    const float* W2 = (const float*)d_in[5];
    const float* b2 = (const float*)d_in[6];
    const float* p2 = (const float*)d_in[7];
    const float* W3 = (const float*)d_in[8];
    const float* b3 = (const float*)d_in[9];
    const float* p3 = (const float*)d_in[10];
    const float* lW1 = (const float*)d_in[11];
    const float* lb1 = (const float*)d_in[12];
    const float* lW2 = (const float*)d_in[13];
    const float* lb2 = (const float*)d_in[14];
    const float* lW3 = (const float*)d_in[15];
    const float* lb3 = (const float*)d_in[16];
    float* gout = (float*)d_out;

    (void)hipFuncSetAttribute((const void*)gnn_pool_kernel,
                              hipFuncAttributeMaxDynamicSharedMemorySize, SMEM_BYTES);

    gnn_pool_kernel<<<NGRAPH, NT, SMEM_BYTES, stream>>>(
        gx, gedge, W1, b1, p1, W2, b2, p2, W3, b3, p3,
        lW1, lb1, lW2, lb2, lW3, lb3, gout);
}

// Round 8
// 287.842 us; speedup vs baseline: 1.2288x; 1.0639x over previous
//
#include <hip/hip_runtime.h>
#include <math.h>

#define NGRAPH 1024
#define NN     256
#define NE     2048
#define EMB    39
#define HD     64
#define NT     512    // 8 waves; 2 blocks/CU (LDS 77.5KB) -> 16 waves/CU; no spill at 128-VGPR budget
#define K1 205
#define K2 164
#define K3 132

// LDS map (bytes): identical to the r3 base (best measured: 185us kernel)
//  feat   256*64*4 = 65536   swizzled rows: 16B-unit u stored at u^(row&7) -> b128 conflict-free
//  red    1024 f   = 4096    aliases epk (ushort[2048])
//  partial 512 f   = 2048    aliases col (uchar[2048]) + ipart (int[512])
//  cnt    260 i    = 1040
//  cur    256 i    = 1024
//  dinv   256 f    = 1024
//  score  256 f    = 1024
//  feats  128 f    = 512
//  pn      64 f    = 256
//  mlp1    64 f    = 256
//  mlp2    32 f    = 128
//  nodemap 256 s   = 512
//  total = 77456  -> 2 blocks/CU
#define SMEM_BYTES 77456

// packed f32 pair: <2 x float> IR ops -> v_pk_fma_f32 / v_pk_max_f32 on gfx950.
// NOT inline asm (r6 lesson: "v" constraints forced SGPR->VGPR movs and blocked
// scheduling). Via IR the backend can keep the uniform W operand in an SGPR pair
// (VOP3P allows one scalar source) and schedule freely. Per-element fma chains
// are preserved -> bit-identical to the scalar fmaf version.
typedef float v2f __attribute__((ext_vector_type(2)));
#define PKFMA(a, b, c) __builtin_elementwise_fma((a), (b), (c))

struct Lds {
    float* feat; float* red; unsigned short* epk;
    float* partial; unsigned char* col; int* ipart;
    int* cnt; int* cur; float* dinv; float* score;
    float* feats; float* pn; float* mlp1; float* mlp2; short* nodemap;
};

// swizzled scalar index: row-major [256][64], 16B unit (j>>2) XORed with row&7
__device__ __forceinline__ int fswz(int row, int k) {
    return row * 64 + (((((k >> 2)) ^ (row & 7)) << 2) | (k & 3));
}

template<int FIN>
__device__ __forceinline__ void layer_body(
    const Lds& S, const int* __restrict__ eb,
    const float* __restrict__ W, const float* __restrict__ bvec,
    const float* __restrict__ pvec, int n, int kkeep, int tid)
{
    const int node = tid & 255;
    const int q    = tid >> 8;       // 0/1: feature half (wave-uniform at runtime)
    // readfirstlane: force SGPR base so W/bias come in via s_load on the scalar pipe
    const int joU  = __builtin_amdgcn_readfirstlane(q * 32);
    const int jb0  = q * 8;          // 16B-unit base of this half
    const int lane = tid & 63;
    const bool active = node < n;

    // B0: zero counts; wave0 computes pn = p/||p||
    if (tid < 258) S.cnt[tid] = 0;
    if (tid < 64) {
        float pv = pvec[tid];
        float s2v = pv * pv;
        #pragma unroll
        for (int off = 32; off >= 1; off >>= 1) s2v += __shfl_xor(s2v, off, 64);
        S.pn[tid] = pv * rsqrtf(s2v);
    }
    __syncthreads();

    // B1: pass1 — remap 4 consecutive orig edges/thread; int-atomic degree count
    {
        const int4* src4 = (const int4*)eb;
        const int4* dst4 = (const int4*)(eb + NE);
        int4 sv = src4[tid];
        int4 dv = dst4[tid];
        int ss[4] = { S.nodemap[sv.x], S.nodemap[sv.y], S.nodemap[sv.z], S.nodemap[sv.w] };
        int dd[4] = { S.nodemap[dv.x], S.nodemap[dv.y], S.nodemap[dv.z], S.nodemap[dv.w] };
        unsigned short pk[4];
        #pragma unroll
        for (int t = 0; t < 4; t++) {
            int s = ss[t], d = dd[t];
            pk[t] = 0xFFFFu;
            if ((s | d) >= 0) {                 // both >= 0
                pk[t] = (unsigned short)(s | (d << 8));
                atomicAdd(&S.cnt[d], 1);        // native ds_add_u32
            }
        }
        *(ushort4*)(S.epk + tid * 4) = make_ushort4(pk[0], pk[1], pk[2], pk[3]);
    }
    __syncthreads();

    // B2: fused — exclusive scan of cnt -> offsets, cursors, dinv (single wave)
    if (tid < 64) {
        int base = tid * 4;
        int4 c = *(const int4*)(S.cnt + base);
        int s4 = c.x + c.y + c.z + c.w;
        int x = s4;
        #pragma unroll
        for (int off = 1; off < 64; off <<= 1) {
            int t = __shfl_up(x, off, 64);
            if (tid >= off) x += t;
        }
        int e0 = x - s4;
        int4 off4 = make_int4(e0, e0 + c.x, e0 + c.x + c.y, e0 + c.x + c.y + c.z);
        *(int4*)(S.cnt + base) = off4;
        *(int4*)(S.cur + base) = off4;
        *(float4*)(S.dinv + base) = make_float4(
            rsqrtf((float)(1 + c.x)), rsqrtf((float)(1 + c.y)),
            rsqrtf((float)(1 + c.z)), rsqrtf((float)(1 + c.w)));
        if (tid == 63) S.cnt[256] = x;
    }
    __syncthreads();

    // B4: CSR fill (int-atomic cursors) + h = x@W (x: b128 LDS, W: s_load; v_pk_fma)
    {
        ushort4 pk4 = *(const ushort4*)(S.epk + tid * 4);
        unsigned short pks[4] = { pk4.x, pk4.y, pk4.z, pk4.w };
        #pragma unroll
        for (int t = 0; t < 4; t++) {
            unsigned pk = pks[t];
            if (pk != 0xFFFFu) {
                int d = pk >> 8;
                int pos = atomicAdd(&S.cur[d], 1);   // ds_add_rtn_u32
                S.col[pos] = (unsigned char)(pk & 0xFFu);
            }
        }
    }
    v2f h2[16];
    if (active) {
        #pragma unroll
        for (int m = 0; m < 16; m++) h2[m] = (v2f)0.f;
        const v2f* Wp2 = (const v2f*)(W + joU);  // uniform base -> s_load_dwordx2 pairs
        const float* xrow = S.feat + node * 64;
        const int rs = node & 7;
        if (FIN == EMB) {
            #pragma unroll
            for (int u = 0; u < 9; u++) {
                float4 xv = *(const float4*)(xrow + ((u ^ rs) << 2));
                float xs[4] = { xv.x, xv.y, xv.z, xv.w };
                #pragma unroll
                for (int t = 0; t < 4; t++) {
                    int k = u * 4 + t;
                    v2f xb = xs[t];              // splat
                    #pragma unroll
                    for (int m = 0; m < 16; m++)
                        h2[m] = PKFMA(xb, Wp2[k * 32 + m], h2[m]);
                }
            }
            #pragma unroll
            for (int k = 36; k < 39; k++) {      // tail: row has only 39 valid cols
                float xv = xrow[((9 ^ rs) << 2) + (k - 36)];
                v2f xb = xv;
                #pragma unroll
                for (int m = 0; m < 16; m++)
                    h2[m] = PKFMA(xb, Wp2[k * 32 + m], h2[m]);
            }
        } else {
            #pragma unroll 4
            for (int u = 0; u < 16; u++) {
                float4 xv = *(const float4*)(xrow + ((u ^ rs) << 2));
                float xs[4] = { xv.x, xv.y, xv.z, xv.w };
                #pragma unroll
                for (int t = 0; t < 4; t++) {
                    int k = u * 4 + t;
                    v2f xb = xs[t];
                    #pragma unroll
                    for (int m = 0; m < 16; m++)
                        h2[m] = PKFMA(xb, Wp2[k * 32 + m], h2[m]);
                }
            }
        }
    }
    __syncthreads();    // all x reads done before any h write (in-place x->h)

    // B4b: write h half (8 x b128); h registers DIE here (self-term re-read in B5)
    if (active) {
        const int rs = node & 7;
        #pragma unroll
        for (int u = 0; u < 8; u++) {
            float4 v;
            *(v2f*)&v.x = h2[2*u];
            *(v2f*)&v.z = h2[2*u+1];
            *(float4*)(S.feat + node * 64 + (((jb0 + u) ^ rs) << 2)) = v;
        }
    }
    __syncthreads();

    // B5: gather agg (v_pk_fma, all-VGPR operands); self-term re-read from own LDS row;
    // out computed IN PLACE of s2
    v2f s2[16];             // becomes `out` after the epilogue loop
    float sc = 0.f;
    if (active) {
        int o0 = S.cnt[node], o1 = S.cnt[node + 1];
        #pragma unroll
        for (int m = 0; m < 16; m++) s2[m] = (v2f)0.f;
        if (o0 < o1) {
            int sN = S.col[o0];                  // prefetch breaks col->hsrc chain
            for (int e = o0; e < o1; e++) {
                int s = sN;
                int en = (e + 1 < o1) ? (e + 1) : e;
                sN = S.col[en];
                float dv = S.dinv[s];
                v2f dvb = dv;                    // splat (1 mov/edge)
                const float* hs = S.feat + s * 64;
                const int ssz = s & 7;
                #pragma unroll
                for (int u = 0; u < 8; u++) {
                    float4 hv = *(const float4*)(hs + (((jb0 + u) ^ ssz) << 2));
                    v2f h01 = *(const v2f*)&hv.x;
                    v2f h23 = *(const v2f*)&hv.z;
                    s2[2*u]   = PKFMA(dvb, h01, s2[2*u]);
                    s2[2*u+1] = PKFMA(dvb, h23, s2[2*u+1]);
                }
            }
        }
        float dvd = S.dinv[node];
        float invdeg = dvd * dvd;               // 1/deg
        v2f dv2 = dvd, iv2 = invdeg;
        const v2f* b2p = (const v2f*)(bvec + joU);   // uniform -> s_load pairs
        const float* hown = S.feat + node * 64;
        const int rs = node & 7;
        #pragma unroll
        for (int u = 0; u < 8; u++) {
            float4 hv = *(const float4*)(hown + (((jb0 + u) ^ rs) << 2));
            v2f h01 = *(const v2f*)&hv.x;
            v2f h23 = *(const v2f*)&hv.z;
            v2f t0 = PKFMA(iv2, h01, b2p[2*u]);
            v2f t1 = PKFMA(iv2, h23, b2p[2*u+1]);
            v2f o0 = PKFMA(dv2, s2[2*u],   t0);
            v2f o1 = PKFMA(dv2, s2[2*u+1], t1);
            o0 = __builtin_elementwise_max(o0, (v2f)0.f);
            o1 = __builtin_elementwise_max(o1, (v2f)0.f);
            s2[2*u] = o0; s2[2*u+1] = o1;        // in place: s2 is now `out`
            // score dot stays scalar-sequential: preserves exact score bits (topk ties)
            int j = u * 4;
            sc = fmaf(o0.x, S.pn[joU + j + 0], sc);
            sc = fmaf(o0.y, S.pn[joU + j + 1], sc);
            sc = fmaf(o1.x, S.pn[joU + j + 2], sc);
            sc = fmaf(o1.y, S.pn[joU + j + 3], sc);
        }
    }
    __syncthreads();    // col + feat reads done -> partial may alias col

    // B6: score partials
    S.partial[tid] = sc;
    __syncthreads();

    // B7: score = tanh(dot)
    if (tid < 256) S.score[tid] = tanhf(S.partial[tid] + S.partial[tid + 256]);
    __syncthreads();

    // B8: rank by counting (2 threads/node, 128-wide slices; b128 broadcast reads)
    {
        int j0 = joU * 4;                        // q*128, scalar
        int j1 = (j0 + 128 < n) ? (j0 + 128) : n;
        float si = S.score[node];
        int c = 0;
        int j = j0;
        for (; j + 4 <= j1; j += 4) {
            float4 s4 = *(const float4*)&S.score[j];
            c += (s4.x > si) || (s4.x == si && (j + 0) < node);
            c += (s4.y > si) || (s4.y == si && (j + 1) < node);
            c += (s4.z > si) || (s4.z == si && (j + 2) < node);
            c += (s4.w > si) || (s4.w == si && (j + 3) < node);
        }
        for (; j < j1; j++) {
            float sj = S.score[j];
            c += (sj > si) || (sj == si && j < node);
        }
        S.ipart[tid] = c;
    }
    __syncthreads();

    // B9: rank into cur (cursors dead)
    if (tid < 256) S.cur[tid] = S.ipart[tid] + S.ipart[tid + 256];
    __syncthreads();

    // B10: compose cumulative nodemap; pooled rows written from out regs (b128, permuted)
    if (tid < 256) {
        int m = S.nodemap[tid];
        if (m >= 0) {
            int r = S.cur[m];
            S.nodemap[tid] = (short)((r < kkeep) ? r : -1);
        }
    }
    if (active) {
        int r = S.cur[node];
        if (r < kkeep) {
            float v = S.score[node];
            v2f vs = v;
            const int rr = r & 7;
            #pragma unroll
            for (int u = 0; u < 8; u++) {
                v2f w01 = s2[2*u]   * vs;        // v_pk_mul_f32, per-element exact
                v2f w23 = s2[2*u+1] * vs;
                float4 w4;
                *(v2f*)&w4.x = w01;
                *(v2f*)&w4.z = w23;
                *(float4*)(S.feat + r * 64 + (((jb0 + u) ^ rr) << 2)) = w4;
            }
        }
    }
    __syncthreads();

    // B11: readout partials (wave-strided rows, lane=feature; row read = bank permutation)
    {
        int w = tid >> 6;
        float mx = -3.4e38f, sm = 0.f;
        for (int rr = w; rr < kkeep; rr += 8) {
            float v = S.feat[rr * 64 + ((((lane >> 2) ^ (rr & 7)) << 2) | (lane & 3))];
            mx = fmaxf(mx, v);
            sm += v;
        }
        S.red[w * 64 + lane]       = mx;
        S.red[512 + w * 64 + lane] = sm;
    }
    __syncthreads();

    // B12: combine into feats
    if (tid < 64) {
        float mx = S.red[tid], sm = S.red[512 + tid];
        #pragma unroll
        for (int w = 1; w < 8; w++) {
            mx = fmaxf(mx, S.red[w * 64 + tid]);
            sm += S.red[512 + w * 64 + tid];
        }
        S.feats[tid]      += mx;
        S.feats[64 + tid] += sm / (float)kkeep;
    }
    __syncthreads();
}

__global__ __launch_bounds__(NT, 4) void gnn_pool_kernel(
    const float* __restrict__ gx, const int* __restrict__ gedge,
    const float* __restrict__ W1, const float* __restrict__ b1, const float* __restrict__ p1,
    const float* __restrict__ W2, const float* __restrict__ b2, const float* __restrict__ p2,
    const float* __restrict__ W3, const float* __restrict__ b3, const float* __restrict__ p3,
    const float* __restrict__ lW1, const float* __restrict__ lb1,
    const float* __restrict__ lW2, const float* __restrict__ lb2,
    const float* __restrict__ lW3, const float* __restrict__ lb3,
    float* __restrict__ gout)
{
    extern __shared__ __align__(16) char smem_raw[];
    Lds S;
    S.feat    = (float*)smem_raw;                         // 16384 f
    S.red     = S.feat + NN * 64;                         // 1024 f
    S.epk     = (unsigned short*)S.red;                   // alias
    S.partial = S.red + 1024;                             // 512 f
    S.col     = (unsigned char*)S.partial;                // alias
    S.ipart   = (int*)S.partial;                          // alias
    S.cnt     = (int*)(S.partial + 512);                  // 260 i
    S.cur     = S.cnt + 260;                              // 256 i
    S.dinv    = (float*)(S.cur + 256);                    // 256 f
    S.score   = S.dinv + 256;                             // 256 f
    S.feats   = S.score + 256;                            // 128 f
    S.pn      = S.feats + 128;                            // 64 f
    S.mlp1    = S.pn + 64;                                // 64 f
    S.mlp2    = S.mlp1 + 64;                              // 32 f
    S.nodemap = (short*)(S.mlp2 + 32);                    // 256 s

    const int tid = threadIdx.x;
    const int b   = blockIdx.x;
    const int* eb = gedge + (size_t)b * 2 * NE;

    // init: x -> swizzled feat rows (float4 global loads), identity nodemap, zero feats
    {
        const float4* xb4 = (const float4*)(gx + (size_t)b * NN * EMB);
        for (int i = tid; i < (NN * EMB) / 4; i += NT) {   // 2496 vec4
            float4 v = xb4[i];
            int g = i * 4;
            float vs[4] = { v.x, v.y, v.z, v.w };
            #pragma unroll
            for (int t = 0; t < 4; t++) {
                int gg = g + t;
                int nd = gg / EMB;
                int k  = gg - nd * EMB;
                S.feat[fswz(nd, k)] = vs[t];
            }
        }
        if (tid < NN) S.nodemap[tid] = (short)tid;
        if (tid < 2 * HD) S.feats[tid] = 0.f;
    }
    __syncthreads();

    layer_body<EMB>(S, eb, W1, b1, p1, NN, K1, tid);
    layer_body<HD >(S, eb, W2, b2, p2, K1, K2, tid);
    layer_body<HD >(S, eb, W3, b3, p3, K2, K3, tid);

    // final MLP: 128 -> 64 -> 32 -> 1, sigmoid
    if (tid < 64) {
        float a = lb1[tid];
        for (int i = 0; i < 2 * HD; i++) a = fmaf(S.feats[i], lW1[i * 64 + tid], a);
        S.mlp1[tid] = fmaxf(a, 0.f);
    }
    __syncthreads();
    if (tid < 32) {
        float a = lb2[tid];
        for (int i = 0; i < 64; i++) a = fmaf(S.mlp1[i], lW2[i * 32 + tid], a);
        S.mlp2[tid] = fmaxf(a, 0.f);
    }
    __syncthreads();
    if (tid == 0) {
        float a = lb3[0];
        for (int i = 0; i < 32; i++) a = fmaf(S.mlp2[i], lW3[i], a);
        gout[b] = 1.0f / (1.0f + expf(-a));
    }
}

extern "C" void kernel_launch(void* const* d_in, const int* in_sizes, int n_in,
                              void* d_out, int out_size, void* d_ws, size_t ws_size,
                              hipStream_t stream) {
    const float* gx    = (const float*)d_in[0];
    const int*   gedge = (const int*)d_in[1];
    const float* W1 = (const float*)d_in[2];
    const float* b1 = (const float*)d_in[3];
    const float* p1 = (const float*)d_in[4];
    const float* W2 = (const float*)d_in[5];
    const float* b2 = (const float*)d_in[6];
    const float* p2 = (const float*)d_in[7];
    const float* W3 = (const float*)d_in[8];
    const float* b3 = (const float*)d_in[9];
    const float* p3 = (const float*)d_in[10];
    const float* lW1 = (const float*)d_in[11];
    const float* lb1 = (const float*)d_in[12];
    const float* lW2 = (const float*)d_in[13];
    const float* lb2 = (const float*)d_in[14];
    const float* lW3 = (const float*)d_in[15];
    const float* lb3 = (const float*)d_in[16];
    float* gout = (float*)d_out;

    (void)hipFuncSetAttribute((const void*)gnn_pool_kernel,
                              hipFuncAttributeMaxDynamicSharedMemorySize, SMEM_BYTES);

    gnn_pool_kernel<<<NGRAPH, NT, SMEM_BYTES, stream>>>(
        gx, gedge, W1, b1, p1, W2, b2, p2, W3, b3, p3,
        lW1, lb1, lW2, lb2, lW3, lb3, gout);
}